// Round 3
// baseline (28919.806 us; speedup 1.0000x reference)
//
#include <hip/hip_runtime.h>
#include <hip/hip_cooperative_groups.h>

namespace cg = cooperative_groups;

typedef unsigned short ushort_t;
typedef __attribute__((ext_vector_type(8))) short bf8;   // 8 bf16 in 4 VGPRs
typedef __attribute__((ext_vector_type(4))) float f4;    // MFMA accumulator

// B=64, T=1024, D=512, H=768, 4H=3072, M=T*B=65536

__device__ __forceinline__ ushort_t f2bf(float f) {
  union { float f; unsigned u; } v; v.f = f;
  unsigned u = v.u + 0x7fffu + ((v.u >> 16) & 1u);   // RNE
  return (ushort_t)(u >> 16);
}
__device__ __forceinline__ float bf2f(ushort_t s) {
  union { unsigned u; float f; } v; v.u = ((unsigned)s) << 16;
  return v.f;
}
__device__ __forceinline__ float sigmf(float x) { return 1.0f / (1.0f + __expf(-x)); }
__device__ __forceinline__ float tanh_f(float x) { return 1.0f - 2.0f / (__expf(2.0f * x) + 1.0f); }

__device__ __forceinline__ void lds_load16(const void* g, void* l) {
  __builtin_amdgcn_global_load_lds(
      (const __attribute__((address_space(1))) unsigned int*)g,
      (__attribute__((address_space(3))) unsigned int*)l, 16, 0, 0);
}

// ---- x [B,T,D] fp32 -> A2 [M=T*B][512] bf16 (time-major rows m = t*64 + b) ----
__global__ __launch_bounds__(256) void k_conv_x(const float* __restrict__ x,
                                                ushort_t* __restrict__ A2) {
  int id = blockIdx.x * 256 + threadIdx.x;          // 0 .. 4194303 (one 8-elem chunk each)
  int m = id >> 6, dc = id & 63;
  int t = m >> 6, b = m & 63;
  const float* src = x + (((size_t)b << 10) + t) * 512 + (dc << 3);
  ushort_t o8[8];
#pragma unroll
  for (int i = 0; i < 8; ++i) o8[i] = f2bf(src[i]);
  *(bf8*)(A2 + ((size_t)m << 9) + (dc << 3)) = *(bf8*)o8;
}

// ---- W [512][3072] fp32 -> B2T [dir][3072][512] bf16 (row = out column n) ----
__global__ __launch_bounds__(256) void k_conv_w(const float* __restrict__ Wf,
                                                const float* __restrict__ Wb,
                                                ushort_t* __restrict__ B2T) {
  int dir = blockIdx.y;
  int id = blockIdx.x * 256 + threadIdx.x;          // 0..196607
  int n = id >> 6, kc = id & 63;
  const float* W = dir ? Wb : Wf;
  int k0 = kc << 3;
  ushort_t o8[8];
#pragma unroll
  for (int i = 0; i < 8; ++i) o8[i] = f2bf(W[(size_t)(k0 + i) * 3072 + n]);
  *(bf8*)(B2T + (size_t)dir * (3072 * 512) + ((size_t)n << 9) + k0) = *(bf8*)o8;
}

// ---- U [768][3072] fp32 -> U2 [dir][g=96][kchunk=96][c=32][8] bf16 ----
// wg g owns hidden units j0=g*8 .. j0+7; its 32 columns are c = gate*8 + jj,
// i.e. U column gate*768 + g*8 + jj.  Layout gives conflict-free ds_read_b128.
__global__ __launch_bounds__(256) void k_conv_u(const float* __restrict__ Uf,
                                                const float* __restrict__ Ub,
                                                ushort_t* __restrict__ U2) {
  int dir = blockIdx.y;
  int id = blockIdx.x * 256 + threadIdx.x;          // 0..294911
  int g = id / 3072;
  int cb = id % 3072;                               // kchunk*32 + c
  int kchunk = cb >> 5, c = cb & 31;
  int ucol = ((c >> 3) * 768) + (g << 3) + (c & 7);
  const float* U = dir ? Ub : Uf;
  int k0 = kchunk << 3;
  ushort_t o8[8];
#pragma unroll
  for (int i = 0; i < 8; ++i) o8[i] = f2bf(U[(size_t)(k0 + i) * 3072 + ucol]);
  *(bf8*)(U2 + (size_t)(dir * 96 + g) * 24576 + ((size_t)cb << 3)) = *(bf8*)o8;
}

// ---- xz[dir][m][n] = A2[m][:] . B2T[dir][n][:] + bias[n]  (bf16 out) ----
// 128x128 tile, BK=32, 4 waves each 64x64, m97-style single-buffer staging.
// LDS layout [kgrp][row][8] -> frag reads are 2-way bank aliased (free).
__global__ __launch_bounds__(256) void k_gemm(const ushort_t* __restrict__ A2,
                                              const ushort_t* __restrict__ B2T,
                                              const float* __restrict__ bf_,
                                              const float* __restrict__ bb_,
                                              ushort_t* __restrict__ XZ) {
  __shared__ ushort_t As[4096];
  __shared__ ushort_t Bs[4096];
  const int tid = threadIdx.x;
  const int m0 = blockIdx.x * 128, n0 = blockIdx.y * 128, dir = blockIdx.z;
  const ushort_t* A = A2;
  const ushort_t* B = B2T + (size_t)dir * (3072 * 512);
  const float* bias = dir ? bb_ : bf_;
  ushort_t* C = XZ + (size_t)dir * ((size_t)65536 * 3072);
  const int w = tid >> 6, lane = tid & 63;
  const int q = lane & 15, g16 = lane >> 4;
  const int wm = (w >> 1) * 64, wn = (w & 1) * 64;
  const f4 zero4 = {0.f, 0.f, 0.f, 0.f};
  f4 acc[4][4];
#pragma unroll
  for (int i = 0; i < 4; ++i)
#pragma unroll
    for (int j = 0; j < 4; ++j) acc[i][j] = zero4;

  for (int kt = 0; kt < 16; ++kt) {
    const int k0 = kt * 32;
#pragma unroll
    for (int i = 0; i < 2; ++i) {
      int ch = i * 256 + tid;                 // 0..511 ; lane-linear LDS dest
      int row = ch & 127, kg = ch >> 7;
      lds_load16(A + (size_t)(m0 + row) * 512 + k0 + (kg << 3), &As[ch << 3]);
      lds_load16(B + (size_t)(n0 + row) * 512 + k0 + (kg << 3), &Bs[ch << 3]);
    }
    __syncthreads();
    bf8 af[4], bfr[4];
#pragma unroll
    for (int i = 0; i < 4; ++i)
      af[i] = *(const bf8*)&As[(g16 << 10) + ((wm + i * 16 + q) << 3)];
#pragma unroll
    for (int j = 0; j < 4; ++j)
      bfr[j] = *(const bf8*)&Bs[(g16 << 10) + ((wn + j * 16 + q) << 3)];
#pragma unroll
    for (int i = 0; i < 4; ++i)
#pragma unroll
      for (int j = 0; j < 4; ++j)
        acc[i][j] = __builtin_amdgcn_mfma_f32_16x16x32_bf16(af[i], bfr[j], acc[i][j], 0, 0, 0);
    __syncthreads();
  }
  // epilogue: C[row][col] = acc + bias[col]   (D row = g16*4+reg, col = q)
#pragma unroll
  for (int j = 0; j < 4; ++j) {
    int col = n0 + wn + j * 16 + q;
    float bv = bias[col];
#pragma unroll
    for (int i = 0; i < 4; ++i) {
      int rowb = m0 + wm + i * 16 + (g16 << 2);
#pragma unroll
      for (int r = 0; r < 4; ++r)
        C[(size_t)(rowb + r) * 3072 + col] = f2bf(acc[i][j][r] + bv);
    }
  }
}

// ---- persistent bidirectional LSTM scan (cooperative) ----
// grid = 192 blocks: dir = bx/96, g = bx%96 owns units j0=g*8..+7 (32 z-cols).
// U-slice resident in LDS; h ping-pong in global (bf16); c in registers.
__global__ __launch_bounds__(256) void k_scan(const ushort_t* __restrict__ U2,
                                              const ushort_t* __restrict__ XZ,
                                              ushort_t* __restrict__ HB,
                                              float* __restrict__ out) {
  __shared__ ushort_t sU[24576];                    // 48 KB
  cg::grid_group grid = cg::this_grid();
  const int tid = threadIdx.x;
  const int bx = blockIdx.x;
  const int dir = bx / 96;
  const int g = bx % 96;
  const int j0 = g << 3;
  const int w = tid >> 6, lane = tid & 63;
  const int q = lane & 15, g16 = lane >> 4, jj = q & 7;
  const ushort_t* U2blk = U2 + (size_t)(dir * 96 + g) * 24576;
  const ushort_t* xzd = XZ + (size_t)dir * ((size_t)65536 * 3072);
  ushort_t* hb0 = HB + (size_t)dir * (2 * 49152);

#pragma unroll
  for (int it = 0; it < 12; ++it) {                 // stage U slice -> LDS (once)
    int ch = it * 256 + tid;
    lds_load16(U2blk + ((size_t)ch << 3), &sU[ch << 3]);
  }
  for (int idx = tid; idx < 512; idx += 256)        // zero own slice of h slot 0
    hb0[(idx >> 3) * 768 + j0 + (idx & 7)] = 0;
  __syncthreads();
  grid.sync();

  const int hrow = w * 16 + q;                      // A-frag row (batch)
  const int kgo = g16 << 3;
  const int colA = ((q >> 3) * 768) + j0 + jj;      // gate i/f column in xz
  const int colB = ((2 + (q >> 3)) * 768) + j0 + jj;// gate g/o column in xz
  const bool lo = (q < 8);
  float creg[4] = {0.f, 0.f, 0.f, 0.f};

  for (int s = 0; s < 1024; ++s) {
    const int t = dir ? (1023 - s) : s;
    const ushort_t* hcur = hb0 + (s & 1) * 49152;
    ushort_t* hnxt = hb0 + ((s & 1) ^ 1) * 49152;

    bf8 areg[24];
#pragma unroll
    for (int ks = 0; ks < 24; ++ks)
      areg[ks] = *(const bf8*)(hcur + hrow * 768 + ks * 32 + kgo);

    f4 acc0 = {0.f, 0.f, 0.f, 0.f}, acc1 = {0.f, 0.f, 0.f, 0.f};
#pragma unroll
    for (int ks = 0; ks < 24; ++ks) {
      int kch = (ks << 2) + g16;
      bf8 b0 = *(const bf8*)&sU[(kch << 8) + (q << 3)];
      bf8 b1 = *(const bf8*)&sU[(kch << 8) + ((q + 16) << 3)];
      acc0 = __builtin_amdgcn_mfma_f32_16x16x32_bf16(areg[ks], b0, acc0, 0, 0, 0);
      acc1 = __builtin_amdgcn_mfma_f32_16x16x32_bf16(areg[ks], b1, acc1, 0, 0, 0);
    }

    const ushort_t* xzt = xzd + ((size_t)(t << 6)) * 3072;
    float z0[4], z1[4];
#pragma unroll
    for (int r = 0; r < 4; ++r) {
      int row = w * 16 + (g16 << 2) + r;
      const ushort_t* xr = xzt + (size_t)row * 3072;
      z0[r] = acc0[r] + bf2f(xr[colA]);
      z1[r] = acc1[r] + bf2f(xr[colB]);
    }
#pragma unroll
    for (int r = 0; r < 4; ++r) {
      float p0 = __shfl_xor(z0[r], 8);
      float p1 = __shfl_xor(z1[r], 8);
      float zi = lo ? z0[r] : p0;
      float zf = lo ? p0 : z0[r];
      float zg = lo ? z1[r] : p1;
      float zo = lo ? p1 : z1[r];
      float ig = sigmf(zi), fg = sigmf(zf), gg = tanh_f(zg), og = sigmf(zo);
      float cc = fg * creg[r] + ig * gg;
      creg[r] = cc;
      float hh = og * tanh_f(cc);
      if (lo) {
        int row = w * 16 + (g16 << 2) + r;
        hnxt[row * 768 + j0 + jj] = f2bf(hh);
        out[((size_t)((row << 10) + t)) * 1536 + dir * 768 + j0 + jj] = hh;
      }
    }
    grid.sync();
  }
}

extern "C" void kernel_launch(void* const* d_in, const int* in_sizes, int n_in,
                              void* d_out, int out_size, void* d_ws, size_t ws_size,
                              hipStream_t stream) {
  (void)in_sizes; (void)n_in; (void)out_size;
  const float* x   = (const float*)d_in[0];
  const float* Wf  = (const float*)d_in[1];
  const float* Uf  = (const float*)d_in[2];
  const float* bf_ = (const float*)d_in[3];
  const float* Wb  = (const float*)d_in[4];
  const float* Ub  = (const float*)d_in[5];
  const float* bb_ = (const float*)d_in[6];
  float* out = (float*)d_out;

  // workspace layout (bytes)
  //  A2 : 67,108,864   B2T: 6,291,456   U2: 9,437,184
  //  XZ : 805,306,368  HB : 393,216     total 888,537,088
  if (ws_size < (size_t)888537088) return;
  char* base = (char*)d_ws;
  ushort_t* A2  = (ushort_t*)(base);
  ushort_t* B2T = (ushort_t*)(base + 67108864);
  ushort_t* U2  = (ushort_t*)(base + 73400320);
  ushort_t* XZ  = (ushort_t*)(base + 82837504);
  ushort_t* HB  = (ushort_t*)(base + 888143872);

  k_conv_x<<<dim3(16384), dim3(256), 0, stream>>>(x, A2);
  k_conv_w<<<dim3(768, 2), dim3(256), 0, stream>>>(Wf, Wb, B2T);
  k_conv_u<<<dim3(1152, 2), dim3(256), 0, stream>>>(Uf, Ub, U2);
  k_gemm<<<dim3(512, 24, 2), dim3(256), 0, stream>>>(A2, B2T, bf_, bb_, XZ);

  void* args[] = {(void*)&U2, (void*)&XZ, (void*)&HB, (void*)&out};
  hipLaunchCooperativeKernel((void*)k_scan, dim3(192), dim3(256), args, 0, stream);
}

// Round 4
// 11036.624 us; speedup vs baseline: 2.6203x; 2.6203x over previous
//
#include <hip/hip_runtime.h>

typedef unsigned short ushort_t;
typedef __attribute__((ext_vector_type(8))) short bf8;   // 8 bf16 in 4 VGPRs
typedef __attribute__((ext_vector_type(4))) float f4;    // MFMA accumulator

// B=64, T=1024, D=512, H=768, 4H=3072, M=T*B=65536

__device__ __forceinline__ ushort_t f2bf(float f) {
  union { float f; unsigned u; } v; v.f = f;
  unsigned u = v.u + 0x7fffu + ((v.u >> 16) & 1u);   // RNE
  return (ushort_t)(u >> 16);
}
__device__ __forceinline__ float bf2f(ushort_t s) {
  union { unsigned u; float f; } v; v.u = ((unsigned)s) << 16;
  return v.f;
}
__device__ __forceinline__ float sigmf(float x) { return 1.0f / (1.0f + __expf(-x)); }
__device__ __forceinline__ float tanh_f(float x) { return 1.0f - 2.0f / (__expf(2.0f * x) + 1.0f); }

__device__ __forceinline__ void lds_load16(const void* g, void* l) {
  __builtin_amdgcn_global_load_lds(
      (const __attribute__((address_space(1))) unsigned int*)g,
      (__attribute__((address_space(3))) unsigned int*)l, 16, 0, 0);
}

// ---- x [B,T,D] fp32 -> A2 [M=T*B][512] bf16 (time-major rows m = t*64 + b) ----
__global__ __launch_bounds__(256) void k_conv_x(const float* __restrict__ x,
                                                ushort_t* __restrict__ A2) {
  int id = blockIdx.x * 256 + threadIdx.x;
  int m = id >> 6, dc = id & 63;
  int t = m >> 6, b = m & 63;
  const float* src = x + (((size_t)b << 10) + t) * 512 + (dc << 3);
  ushort_t o8[8];
#pragma unroll
  for (int i = 0; i < 8; ++i) o8[i] = f2bf(src[i]);
  *(bf8*)(A2 + ((size_t)m << 9) + (dc << 3)) = *(bf8*)o8;
}

// ---- W [512][3072] fp32 -> B2T [dir][3072][512] bf16 (row = out column n) ----
__global__ __launch_bounds__(256) void k_conv_w(const float* __restrict__ Wf,
                                                const float* __restrict__ Wb,
                                                ushort_t* __restrict__ B2T) {
  int dir = blockIdx.y;
  int id = blockIdx.x * 256 + threadIdx.x;
  int n = id >> 6, kc = id & 63;
  const float* W = dir ? Wb : Wf;
  int k0 = kc << 3;
  ushort_t o8[8];
#pragma unroll
  for (int i = 0; i < 8; ++i) o8[i] = f2bf(W[(size_t)(k0 + i) * 3072 + n]);
  *(bf8*)(B2T + (size_t)dir * (3072 * 512) + ((size_t)n << 9) + k0) = *(bf8*)o8;
}

// ---- U [768][3072] fp32 -> U2 [dir][g=48][gate=4][ks=24][lane=64][e=8] bf16 ----
// block g owns hidden units j0=g*16..+15.  B-frag for (gate,ks) at lane l:
// col = gate*768 + g*16 + (l&15), k = ks*32 + (l>>4)*8 + e.
__global__ __launch_bounds__(256) void k_conv_u(const float* __restrict__ Uf,
                                                const float* __restrict__ Ub,
                                                ushort_t* __restrict__ U2) {
  int dir = blockIdx.y;
  int id = blockIdx.x * 256 + threadIdx.x;          // 0..294911 (chunks of 8)
  int lane = id & 63;
  int rest = id >> 6;                               // 0..4607
  int ks = rest % 24;
  int rest2 = rest / 24;                            // 0..191
  int gate = rest2 & 3;
  int g48 = rest2 >> 2;                             // 0..47
  const float* U = dir ? Ub : Uf;
  int col = gate * 768 + g48 * 16 + (lane & 15);
  int kbase = ks * 32 + (lane >> 4) * 8;
  ushort_t o8[8];
#pragma unroll
  for (int e = 0; e < 8; ++e) o8[e] = f2bf(U[(size_t)(kbase + e) * 3072 + col]);
  size_t idx = (size_t)(dir * 48 + g48) * 49152 + (size_t)(((gate * 24 + ks) << 6) + lane) * 8;
  *(bf8*)(U2 + idx) = *(bf8*)o8;
}

// ---- GEMM: xz = A2 . B2T^T + bias, written in scan-native XZ3 layout ----
// XZ3[dir] tiles: [(t*48+g)][tid(256)][e(16)] ushort; e = gate*4 + r where the
// scan thread tid=(w*64+g16*16+q) consumes z[row=w*16+g16*4+r][gate*768+g*16+q].
__global__ __launch_bounds__(256) void k_gemm(const ushort_t* __restrict__ A2,
                                              const ushort_t* __restrict__ B2T,
                                              const float* __restrict__ bf_,
                                              const float* __restrict__ bb_,
                                              ushort_t* __restrict__ XZ3) {
  __shared__ ushort_t As[4096];
  __shared__ ushort_t Bs[4096];
  const int tid = threadIdx.x;
  const int m0 = blockIdx.x * 128, n0 = blockIdx.y * 128, dir = blockIdx.z;
  const ushort_t* A = A2;
  const ushort_t* B = B2T + (size_t)dir * (3072 * 512);
  const float* bias = dir ? bb_ : bf_;
  ushort_t* C = XZ3 + (size_t)dir * ((size_t)65536 * 3072);
  const int w = tid >> 6, lane = tid & 63;
  const int q = lane & 15, g16 = lane >> 4;
  const int wm = (w >> 1) * 64, wn = (w & 1) * 64;
  const f4 zero4 = {0.f, 0.f, 0.f, 0.f};
  f4 acc[4][4];
#pragma unroll
  for (int i = 0; i < 4; ++i)
#pragma unroll
    for (int j = 0; j < 4; ++j) acc[i][j] = zero4;

  for (int kt = 0; kt < 16; ++kt) {
    const int k0 = kt * 32;
#pragma unroll
    for (int i = 0; i < 2; ++i) {
      int ch = i * 256 + tid;
      int row = ch & 127, kg = ch >> 7;
      lds_load16(A + (size_t)(m0 + row) * 512 + k0 + (kg << 3), &As[ch << 3]);
      lds_load16(B + (size_t)(n0 + row) * 512 + k0 + (kg << 3), &Bs[ch << 3]);
    }
    __syncthreads();
    bf8 af[4], bfr[4];
#pragma unroll
    for (int i = 0; i < 4; ++i)
      af[i] = *(const bf8*)&As[(g16 << 10) + ((wm + i * 16 + q) << 3)];
#pragma unroll
    for (int j = 0; j < 4; ++j)
      bfr[j] = *(const bf8*)&Bs[(g16 << 10) + ((wn + j * 16 + q) << 3)];
#pragma unroll
    for (int i = 0; i < 4; ++i)
#pragma unroll
      for (int j = 0; j < 4; ++j)
        acc[i][j] = __builtin_amdgcn_mfma_f32_16x16x32_bf16(af[i], bfr[j], acc[i][j], 0, 0, 0);
    __syncthreads();
  }
  // epilogue -> XZ3 scan-native layout
#pragma unroll
  for (int j = 0; j < 4; ++j) {
    int col = n0 + wn + j * 16 + q;
    float bv = bias[col];
    int gate = col / 768;
    int within = col - gate * 768;
    int g48 = within >> 4, u = within & 15;
#pragma unroll
    for (int i = 0; i < 4; ++i) {
      int m_base = m0 + wm + i * 16 + (g16 << 2);
#pragma unroll
      for (int r = 0; r < 4; ++r) {
        int m = m_base + r;
        int t = m >> 6, brow = m & 63;
        int tid2 = ((brow >> 4) << 6) + (((brow >> 2) & 3) << 4) + u;
        int e = (gate << 2) + r;
        C[(((size_t)t * 48 + g48) << 12) + (tid2 << 4) + e] = f2bf(acc[i][j][r] + bv);
      }
    }
  }
}

// ---- persistent bidirectional LSTM scan, custom flag barrier ----
// 96 blocks: dir = bx/48, g = bx%48 owns 16 hidden units (64 z-cols, all gates).
// U in dynamic LDS (96KB); h exchange via agent-scope (sc1) 8B atomics — no L2
// flush; arrive = relaxed fetch_add after explicit vmcnt drain; release flag.
__global__ __launch_bounds__(256) void k_scan(const ushort_t* __restrict__ U2,
                                              const ushort_t* __restrict__ XZ3,
                                              ushort_t* __restrict__ HB,
                                              float* __restrict__ out,
                                              unsigned* __restrict__ flags) {
  extern __shared__ ushort_t smem[];
  ushort_t* sU = smem;            // 49152 ushorts = 96 KB
  ushort_t* sH = smem + 49152;    // 1024 ushorts  = 2 KB
  const int tid = threadIdx.x;
  const int bx = blockIdx.x;                        // 0..95
  const int dir = bx / 48;
  const int g = bx - dir * 48;
  const int j0 = g << 4;
  const int lane = tid & 63, w = tid >> 6;
  const int q = lane & 15, g16 = lane >> 4;
  const ushort_t* U2blk = U2 + (size_t)(dir * 48 + g) * 49152;
  const ushort_t* XZ3d = XZ3 + (size_t)dir * ((size_t)65536 * 3072);
  ushort_t* hb0 = HB + (size_t)dir * 98304;         // 2 slots x 49152
  unsigned* arr = flags + dir * 32;                 // 128B apart
  unsigned* rel = flags + 64 + dir * 32;

#pragma unroll
  for (int it = 0; it < 24; ++it) {                 // stage U slice -> LDS once
    int ch = it * 256 + tid;
    lds_load16(U2blk + ((size_t)ch << 3), &sU[ch << 3]);
  }
  __syncthreads();

  float creg[4] = {0.f, 0.f, 0.f, 0.f};
  // prefetch xz for s=0
  {
    int t0 = dir ? 1023 : 0;
    (void)t0;
  }
  const int t_first = dir ? 1023 : 0;
  const ushort_t* tp0 = XZ3d + (((size_t)t_first * 48 + g) << 12) + (tid << 4);
  bf8 xlo = *(const bf8*)tp0;
  bf8 xhi = *(const bf8*)(tp0 + 8);

  const int hrow = w * 16 + q;

  for (int s = 0; s < 1024; ++s) {
    const int t = dir ? (1023 - s) : s;
    const ushort_t* hcur = hb0 + (s & 1) * 49152;
    ushort_t* hnxt = hb0 + ((s & 1) ^ 1) * 49152;

    if (tid == 0) {
      while ((int)__hip_atomic_load(rel, __ATOMIC_RELAXED, __HIP_MEMORY_SCOPE_AGENT) < s)
        __builtin_amdgcn_s_sleep(2);
    }
    __syncthreads();

    // --- read full h(s): 48 x 8B agent loads, issued before MFMA ---
    union AReg { unsigned long long u[2]; bf8 v; };
    AReg areg[24];
    const ushort_t* hp = hcur + hrow * 768 + (g16 << 3);
#pragma unroll
    for (int ks = 0; ks < 24; ++ks) {
      areg[ks].u[0] = __hip_atomic_load((const unsigned long long*)(hp + ks * 32),
                                        __ATOMIC_RELAXED, __HIP_MEMORY_SCOPE_AGENT);
      areg[ks].u[1] = __hip_atomic_load((const unsigned long long*)(hp + ks * 32 + 4),
                                        __ATOMIC_RELAXED, __HIP_MEMORY_SCOPE_AGENT);
    }
    __builtin_amdgcn_sched_barrier(0);

    f4 acc[4];
#pragma unroll
    for (int gate = 0; gate < 4; ++gate) acc[gate] = (f4){0.f, 0.f, 0.f, 0.f};
#pragma unroll
    for (int ks = 0; ks < 24; ++ks) {
#pragma unroll
      for (int gate = 0; gate < 4; ++gate) {
        bf8 bfrag = *(const bf8*)&sU[(size_t)((((gate * 24 + ks) << 6) + lane) << 3)];
        acc[gate] = __builtin_amdgcn_mfma_f32_16x16x32_bf16(areg[ks].v, bfrag, acc[gate], 0, 0, 0);
      }
    }

    // --- gates: this thread owns unit q, rows w*16+g16*4+r (all 4 gates) ---
#pragma unroll
    for (int r = 0; r < 4; ++r) {
      float zi = acc[0][r] + bf2f((ushort_t)xlo[r]);
      float zf = acc[1][r] + bf2f((ushort_t)xlo[4 + r]);
      float zg = acc[2][r] + bf2f((ushort_t)xhi[r]);
      float zo = acc[3][r] + bf2f((ushort_t)xhi[4 + r]);
      float ig = sigmf(zi), fg = sigmf(zf), gg = tanh_f(zg), og = sigmf(zo);
      float cc = fg * creg[r] + ig * gg;
      creg[r] = cc;
      float hh = og * tanh_f(cc);
      int row = w * 16 + (g16 << 2) + r;
      sH[(row << 4) + q] = f2bf(hh);
      out[((size_t)((row << 10) + t)) * 1536 + dir * 768 + j0 + q] = hh;
    }
    __syncthreads();

    // --- publish h(s+1) slice: 256 x 8B agent stores ---
    {
      int row = tid >> 2, ug = tid & 3;
      unsigned long long val = *(const unsigned long long*)&sH[(row << 4) + (ug << 2)];
      __hip_atomic_store((unsigned long long*)(hnxt + row * 768 + j0 + (ug << 2)), val,
                         __ATOMIC_RELAXED, __HIP_MEMORY_SCOPE_AGENT);
    }
    asm volatile("s_waitcnt vmcnt(0)" ::: "memory");
    __syncthreads();
    if (tid == 0) {
      unsigned old = __hip_atomic_fetch_add(arr, 1u, __ATOMIC_RELAXED, __HIP_MEMORY_SCOPE_AGENT);
      if (old == (unsigned)(48 * (s + 1) - 1))
        __hip_atomic_store(rel, (unsigned)(s + 1), __ATOMIC_RELAXED, __HIP_MEMORY_SCOPE_AGENT);
    }

    // --- prefetch next step's xz under the barrier wait ---
    int tn = dir ? (1022 - s) : (s + 1);
    if (tn < 0) tn = 0;
    if (tn > 1023) tn = 1023;
    const ushort_t* tpn = XZ3d + (((size_t)tn * 48 + g) << 12) + (tid << 4);
    xlo = *(const bf8*)tpn;
    xhi = *(const bf8*)(tpn + 8);
    __builtin_amdgcn_sched_barrier(0);
  }
}

extern "C" void kernel_launch(void* const* d_in, const int* in_sizes, int n_in,
                              void* d_out, int out_size, void* d_ws, size_t ws_size,
                              hipStream_t stream) {
  (void)in_sizes; (void)n_in; (void)out_size;
  const float* x   = (const float*)d_in[0];
  const float* Wf  = (const float*)d_in[1];
  const float* Uf  = (const float*)d_in[2];
  const float* bf_ = (const float*)d_in[3];
  const float* Wb  = (const float*)d_in[4];
  const float* Ub  = (const float*)d_in[5];
  const float* bb_ = (const float*)d_in[6];
  float* out = (float*)d_out;

  // workspace layout (bytes)
  //  A2 : 67,108,864   B2T: 6,291,456   U2: 9,437,184
  //  XZ3: 805,306,368  HB : 393,216     flags: 512     total 888,537,600
  if (ws_size < (size_t)888537600) return;
  char* base = (char*)d_ws;
  ushort_t* A2   = (ushort_t*)(base);
  ushort_t* B2T  = (ushort_t*)(base + 67108864);
  ushort_t* U2   = (ushort_t*)(base + 73400320);
  ushort_t* XZ3  = (ushort_t*)(base + 82837504);
  ushort_t* HB   = (ushort_t*)(base + 888143872);
  unsigned* flags = (unsigned*)(base + 888537088);

  // zero h(0) slots and barrier state (ws is re-poisoned before every launch)
  hipMemsetAsync(HB, 0, 393216, stream);
  hipMemsetAsync(flags, 0, 512, stream);

  k_conv_x<<<dim3(16384), dim3(256), 0, stream>>>(x, A2);
  k_conv_w<<<dim3(768, 2), dim3(256), 0, stream>>>(Wf, Wb, B2T);
  k_conv_u<<<dim3(1152, 2), dim3(256), 0, stream>>>(Uf, Ub, U2);
  k_gemm<<<dim3(512, 24, 2), dim3(256), 0, stream>>>(A2, B2T, bf_, bb_, XZ3);

  hipFuncSetAttribute((const void*)k_scan,
                      hipFuncAttributeMaxDynamicSharedMemorySize, 100352);
  void* args[] = {(void*)&U2, (void*)&XZ3, (void*)&HB, (void*)&out, (void*)&flags};
  hipLaunchCooperativeKernel((void*)k_scan, dim3(96), dim3(256), args, 100352, stream);
}